// Round 3
// baseline (6202.058 us; speedup 1.0000x reference)
//
#include <hip/hip_runtime.h>
#include <hip/hip_bf16.h>

// ---------------------------------------------------------------------------
// Problem constants
// ---------------------------------------------------------------------------
#define NA 5000           // atoms
#define NE 40000          // edges
// DA=128, DV=96, DD=64, NL=8, L=2

// ---------------------------------------------------------------------------
// Workspace layout (float indices)
// ---------------------------------------------------------------------------
static const int POFF[13] = {0, 131072, 229376, 294912, 368640, 466944, 516096,
                             589824, 663552, 696320, 761856, 811008, 843776};
#define PT_TOTAL 892928
#define A_OFF    892928          // a  [2][NA][128]
#define V_OFF    2172928         // v  [2][NA][288]
#define D_OFF    5052928         // d  [2][NA][576]
#define BA_OFF   10812928
#define BV_OFF   12092928
#define BD_OFF   14972928
#define PHI_OFF  20732928        // [NE][12] rad0..7, rh0..2, pad
#define PSIA_OFF 21212928        // [NE sorted][2][128]
#define PSIV_OFF 31452928        // [NE sorted][2][288]
#define INT_OFF  54492928        // int region below (as int index from here)
// int region (indices into (int*)(ws + INT_OFF))
#define ICNT  0                  // [NA]
#define IOFF  5120               // [NA+1]
#define ICUR  10240              // [NA]
#define IEIDX 15360              // [NE]
#define ISRC  55360              // [NE] src gathered in sorted order

// output layout (floats)
#define OUT_V 640000
#define OUT_D 2080000

#define OFF_000 POFF[0]
#define OFF_110 POFF[1]
#define OFF_220 POFF[2]
#define OFF_011 POFF[3]
#define OFF_101 POFF[4]
#define OFF_121 POFF[5]
#define OFF_211 POFF[6]
#define OFF_111 POFF[7]
#define OFF_022 POFF[8]
#define OFF_202 POFF[9]
#define OFF_112 POFF[10]
#define OFF_222 POFF[11]
#define OFF_212 POFF[12]

__device__ __forceinline__ float dot4f(float4 a, float4 b) {
  return a.x*b.x + a.y*b.y + a.z*b.z + a.w*b.w;
}
__device__ __forceinline__ float lrelu(float x) { return x > 0.f ? x : 0.1f*x; }

// ---------------------------------------------------------------------------
// P transpose: src [O][8][C] -> dst [C][O][8]
// ---------------------------------------------------------------------------
__global__ __launch_bounds__(256) void transposeP_kernel(
    const float* __restrict__ src, float* __restrict__ dst, int O, int C)
{
  int idx = blockIdx.x * 256 + threadIdx.x;
  if (idx >= O * C) return;
  int o = idx / C, c = idx % C;
#pragma unroll
  for (int k = 0; k < 8; ++k)
    dst[((size_t)c * O + o) * 8 + k] = src[((size_t)o * 8 + k) * C + c];
}

// ---------------------------------------------------------------------------
// Sorting: counting sort of edges by dst
// ---------------------------------------------------------------------------
__global__ __launch_bounds__(256) void hist_kernel(const int* __restrict__ dst, int* __restrict__ cnt) {
  int e = blockIdx.x * 256 + threadIdx.x;
  if (e < NE) atomicAdd(&cnt[dst[e]], 1);
}

__global__ __launch_bounds__(256) void scan_kernel(const int* __restrict__ cnt, int* __restrict__ off) {
  __shared__ int part[256];
  const int t = threadIdx.x;
  int loc[20]; int s = 0;
#pragma unroll
  for (int i = 0; i < 20; ++i) {
    int idx = t * 20 + i;
    int v = (idx < NA) ? cnt[idx] : 0;
    loc[i] = v; s += v;
  }
  part[t] = s; __syncthreads();
  for (int ofs = 1; ofs < 256; ofs <<= 1) {
    int v = (t >= ofs) ? part[t - ofs] : 0;
    __syncthreads();
    part[t] += v;
    __syncthreads();
  }
  int run = part[t] - s;   // exclusive prefix
#pragma unroll
  for (int i = 0; i < 20; ++i) {
    int idx = t * 20 + i;
    if (idx < NA) off[idx] = run;
    run += loc[i];
  }
  if (t == 255) off[NA] = run;
}

__global__ __launch_bounds__(256) void sort_scatter_kernel(
    const int* __restrict__ dst, const int* __restrict__ off,
    int* __restrict__ cur, int* __restrict__ eidx)
{
  int e = blockIdx.x * 256 + threadIdx.x;
  if (e >= NE) return;
  int d = dst[e];
  int pos = off[d] + atomicAdd(&cur[d], 1);
  eidx[pos] = e;
}

// per sorted edge: rad[8], rh[3]; gather src
__global__ __launch_bounds__(256) void phi_kernel(
    const int* __restrict__ eidx, const int* __restrict__ src,
    const float* __restrict__ r_ij, float* __restrict__ phi, int* __restrict__ srcs)
{
  int p = blockIdx.x * 256 + threadIdx.x;
  if (p >= NE) return;
  int e = eidx[p];
  const float rx = r_ij[e*3+0], ry = r_ij[e*3+1], rz = r_ij[e*3+2];
  const float r2 = rx*rx + ry*ry + rz*rz;
  const float r = sqrtf(r2 + 1e-12f);
#pragma unroll
  for (int k = 0; k < 8; ++k) {
    const float z = 7.f*r - (float)k;
    phi[(size_t)p*12 + k] = expf(-0.5f*z*z);
  }
  const float nn = sqrtf(49.f*r2 + 1e-12f);
  const float sc = (2.f / (1.f + expf(-nn)) - 1.f) / nn;
  phi[(size_t)p*12 + 8]  = 7.f*rx*sc;
  phi[(size_t)p*12 + 9]  = 7.f*ry*sc;
  phi[(size_t)p*12 + 10] = 7.f*rz*sc;
  phi[(size_t)p*12 + 11] = 0.f;
  srcs[p] = src[e];
}

// ---------------------------------------------------------------------------
// Input projection (per atom)
// ---------------------------------------------------------------------------
__global__ __launch_bounds__(256) void proj_in_kernel(
    const float* __restrict__ x_a, const float* __restrict__ x_v, const float* __restrict__ x_d,
    const float* __restrict__ Wa, const float* __restrict__ Wv, const float* __restrict__ Wd,
    float* __restrict__ a_ws, float* __restrict__ v_ws, float* __restrict__ d_ws)
{
  __shared__ float xs[992];  // xa[128] xv[288] xd[576]
  const int n = blockIdx.x, t = threadIdx.x;
  for (int q = t; q < 128; q += 256) xs[q]       = x_a[(size_t)n*128 + q];
  for (int q = t; q < 288; q += 256) xs[128 + q] = x_v[(size_t)n*288 + q];
  for (int q = t; q < 576; q += 256) xs[416 + q] = x_d[(size_t)n*576 + q];
  __syncthreads();
  {
    const float* W = &Wa[(size_t)t * 128];
    float acc = 0.f;
    for (int c = 0; c < 128; c += 4) acc += dot4f(*(const float4*)&W[c], *(const float4*)&xs[c]);
    int l = t >> 7, o = t & 127;
    a_ws[((size_t)l*NA + n)*128 + o] = acc;
  }
  if (t < 192) {
    const float* W = &Wv[(size_t)t * 96];
    float a0 = 0.f, a1 = 0.f, a2 = 0.f;
    for (int c = 0; c < 96; ++c) {
      float w = W[c]; const float* x = &xs[128 + c*3];
      a0 = fmaf(w, x[0], a0); a1 = fmaf(w, x[1], a1); a2 = fmaf(w, x[2], a2);
    }
    int l = t / 96, o = t % 96;
    float* dstp = &v_ws[(((size_t)l*NA + n)*96 + o)*3];
    dstp[0] = a0; dstp[1] = a1; dstp[2] = a2;
  }
  if (t < 128) {
    const float* W = &Wd[(size_t)t * 64];
    float acc[9] = {0,0,0,0,0,0,0,0,0};
    for (int c = 0; c < 64; ++c) {
      float w = W[c]; const float* x = &xs[416 + c*9];
#pragma unroll
      for (int j = 0; j < 9; ++j) acc[j] = fmaf(w, x[j], acc[j]);
    }
    int l = t >> 6, o = t & 63;
    float* dstp = &d_ws[(((size_t)l*NA + n)*64 + o)*9];
#pragma unroll
    for (int j = 0; j < 9; ++j) dstp[j] = acc[j];
  }
}

// ---------------------------------------------------------------------------
// Z helpers.  Pt layout [C][O][8].
// ---------------------------------------------------------------------------
template<int O, int C, int NMU>
__device__ __forceinline__ void zcompute(const float* __restrict__ Pt,
    const float* __restrict__ xl, int o, float z[8][NMU])
{
#pragma unroll
  for (int k = 0; k < 8; ++k)
#pragma unroll
    for (int m = 0; m < NMU; ++m) z[k][m] = 0.f;
  const float* p = Pt + o * 8;
#pragma unroll 2
  for (int c = 0; c < C; ++c, p += O*8) {
    const float4 pa = *(const float4*)p;
    const float4 pb = *(const float4*)(p + 4);
#pragma unroll
    for (int m = 0; m < NMU; ++m) {
      const float xv = xl[c * NMU + m];
      z[0][m] = fmaf(pa.x, xv, z[0][m]);
      z[1][m] = fmaf(pa.y, xv, z[1][m]);
      z[2][m] = fmaf(pa.z, xv, z[2][m]);
      z[3][m] = fmaf(pa.w, xv, z[3][m]);
      z[4][m] = fmaf(pb.x, xv, z[4][m]);
      z[5][m] = fmaf(pb.y, xv, z[5][m]);
      z[6][m] = fmaf(pb.z, xv, z[6][m]);
      z[7][m] = fmaf(pb.w, xv, z[7][m]);
    }
  }
}

// two atoms at once (2x flop per Pt byte)
template<int O, int C, int NMU>
__device__ __forceinline__ void zcompute2(const float* __restrict__ Pt,
    const float* __restrict__ x0, const float* __restrict__ x1,
    int o, float z[8][NMU][2])
{
#pragma unroll
  for (int k = 0; k < 8; ++k)
#pragma unroll
    for (int m = 0; m < NMU; ++m) { z[k][m][0] = 0.f; z[k][m][1] = 0.f; }
  const float* p = Pt + o * 8;
#pragma unroll 2
  for (int c = 0; c < C; ++c, p += O*8) {
    const float4 pa = *(const float4*)p;
    const float4 pb = *(const float4*)(p + 4);
#pragma unroll
    for (int m = 0; m < NMU; ++m) {
      const float a0 = x0[c*NMU + m], a1 = x1[c*NMU + m];
      z[0][m][0] = fmaf(pa.x, a0, z[0][m][0]); z[0][m][1] = fmaf(pa.x, a1, z[0][m][1]);
      z[1][m][0] = fmaf(pa.y, a0, z[1][m][0]); z[1][m][1] = fmaf(pa.y, a1, z[1][m][1]);
      z[2][m][0] = fmaf(pa.z, a0, z[2][m][0]); z[2][m][1] = fmaf(pa.z, a1, z[2][m][1]);
      z[3][m][0] = fmaf(pa.w, a0, z[3][m][0]); z[3][m][1] = fmaf(pa.w, a1, z[3][m][1]);
      z[4][m][0] = fmaf(pb.x, a0, z[4][m][0]); z[4][m][1] = fmaf(pb.x, a1, z[4][m][1]);
      z[5][m][0] = fmaf(pb.y, a0, z[5][m][0]); z[5][m][1] = fmaf(pb.y, a1, z[5][m][1]);
      z[6][m][0] = fmaf(pb.z, a0, z[6][m][0]); z[6][m][1] = fmaf(pb.z, a1, z[6][m][1]);
      z[7][m][0] = fmaf(pb.w, a0, z[7][m][0]); z[7][m][1] = fmaf(pb.w, a1, z[7][m][1]);
    }
  }
}

// two atoms, NMU=9, half the k range (register relief)
template<int O, int C>
__device__ __forceinline__ void zcompute2_k4(const float* __restrict__ Pt,
    const float* __restrict__ x0, const float* __restrict__ x1,
    int o, int kh, float z[4][9][2])
{
#pragma unroll
  for (int k = 0; k < 4; ++k)
#pragma unroll
    for (int m = 0; m < 9; ++m) { z[k][m][0] = 0.f; z[k][m][1] = 0.f; }
  const float* p = Pt + o * 8 + kh * 4;
#pragma unroll 2
  for (int c = 0; c < C; ++c, p += O*8) {
    const float4 pa = *(const float4*)p;
#pragma unroll
    for (int m = 0; m < 9; ++m) {
      const float a0 = x0[c*9 + m], a1 = x1[c*9 + m];
      z[0][m][0] = fmaf(pa.x, a0, z[0][m][0]); z[0][m][1] = fmaf(pa.x, a1, z[0][m][1]);
      z[1][m][0] = fmaf(pa.y, a0, z[1][m][0]); z[1][m][1] = fmaf(pa.y, a1, z[1][m][1]);
      z[2][m][0] = fmaf(pa.z, a0, z[2][m][0]); z[2][m][1] = fmaf(pa.z, a1, z[2][m][1]);
      z[3][m][0] = fmaf(pa.w, a0, z[3][m][0]); z[3][m][1] = fmaf(pa.w, a1, z[3][m][1]);
    }
  }
}

template<int NMU>
__device__ __forceinline__ float kdot(const float z[8][NMU], int m, const float* rr) {
  float s = z[0][m] * rr[0];
#pragma unroll
  for (int k = 1; k < 8; ++k) s = fmaf(z[k][m], rr[k], s);
  return s;
}

template<int NMU>
__device__ __forceinline__ float kdot2(const float z[8][NMU][2], int m, int a, const float* rr) {
  float s = z[0][m][a] * rr[0];
#pragma unroll
  for (int k = 1; k < 8; ++k) s = fmaf(z[k][m][a], rr[k], s);
  return s;
}

__device__ __forceinline__ float kdot2_k4(const float z[4][9][2], int m, int a, const float* rr) {
  float s = z[0][m][a] * rr[0];
#pragma unroll
  for (int k = 1; k < 4; ++k) s = fmaf(z[k][m][a], rr[k], s);
  return s;
}

// shared feature layout for pass kernels (floats)
// S_XA [a][l][128] = 512 | S_XV [a][l][288] = 1152 | S_XD [a][l][576] = 2304 | phi
#define F_XA 0
#define F_XV 512
#define F_XD 1664
#define F_PHI 3968

template<int NT>
__device__ __forceinline__ void load_features(float* sm, int t, int n0, int n1,
    const float* __restrict__ a_ws, const float* __restrict__ v_ws, const float* __restrict__ d_ws)
{
  const int na[2] = {n0, n1};
  for (int q = t; q < 512; q += NT) {
    const int a = q >> 8, r = q & 255;
    sm[F_XA + q] = a_ws[((size_t)(r>>7)*NA + na[a])*128 + (r & 127)];
  }
  for (int q = t; q < 1152; q += NT) {
    const int a = q / 576, r = q % 576;
    sm[F_XV + q] = v_ws[((size_t)(r/288)*NA + na[a])*288 + (r % 288)];
  }
  for (int q = t; q < 2304; q += NT) {
    const int a = q / 1152, r = q % 1152;
    sm[F_XD + q] = d_ws[((size_t)(r/576)*NA + na[a])*576 + (r % 576)];
  }
}

// ---------------------------------------------------------------------------
// Pass A: psi_a (terms 000,110,220). One block per atom pair. 256 thr.
// ---------------------------------------------------------------------------
__global__ __launch_bounds__(256, 2) void pass_a_kernel(
    const int* __restrict__ off, const float* __restrict__ phi,
    const float* __restrict__ Pt,
    const float* __restrict__ a_ws, const float* __restrict__ v_ws, const float* __restrict__ d_ws,
    float* __restrict__ psiA)
{
  __shared__ float sm[3968 + 384];
  const int t = threadIdx.x;
  const int n0 = blockIdx.x * 2, n1 = n0 + 1;
  const int off0 = off[n0], off1 = off[n1], off2 = off[n1 + 1];
  const int d0 = off1 - off0, d1 = off2 - off1;
  const int dm = d0 > d1 ? d0 : d1;
  if (dm == 0) return;
  const int o = t & 127, l = t >> 7;
  load_features<256>(sm, t, n0, n1, a_ws, v_ws, d_ws);
  const float* xa0 = &sm[F_XA + l*128];
  const float* xa1 = &sm[F_XA + 256 + l*128];
  const float* xv0 = &sm[F_XV + l*288];
  const float* xv1 = &sm[F_XV + 576 + l*288];
  const float* xd0 = &sm[F_XD + l*576];
  const float* xd1 = &sm[F_XD + 1152 + l*576];
  float* sphi = &sm[F_PHI];

  const int nw = (dm + 15) >> 4;
  for (int w = 0; w < nw; ++w) {
    const int b0 = w * 16;
    const int E0 = min(16, max(0, d0 - b0));
    const int E1 = min(16, max(0, d1 - b0));
    __syncthreads();
    for (int q = t; q < 384; q += 256) {
      const int s = q / 12, f = q % 12, a = s >> 4, e = s & 15;
      const int E = a ? E1 : E0;
      const int gp = (a ? off1 : off0) + b0 + e;
      sphi[q] = (e < E) ? phi[(size_t)gp * 12 + f] : 0.f;
    }
    __syncthreads();
    float psi[32];
#pragma unroll
    for (int i = 0; i < 32; ++i) psi[i] = 0.f;

    { // 000: a input
      float z[8][1][2];
      zcompute2<128,128,1>(Pt + OFF_000, xa0, xa1, o, z);
      for (int a = 0; a < 2; ++a) {
        const int E = a ? E1 : E0;
        for (int e = 0; e < E; ++e) {
          const float* ph = &sphi[(a*16 + e)*12];
          psi[a*16 + e] += kdot2<1>(z, 0, a, ph);
        }
      }
    }
    { // 110: v input
      float z[8][3][2];
      zcompute2<128,96,3>(Pt + OFF_110, xv0, xv1, o, z);
      for (int a = 0; a < 2; ++a) {
        const int E = a ? E1 : E0;
        for (int e = 0; e < E; ++e) {
          const float* ph = &sphi[(a*16 + e)*12];
          const float s0 = kdot2<3>(z, 0, a, ph), s1 = kdot2<3>(z, 1, a, ph), s2 = kdot2<3>(z, 2, a, ph);
          psi[a*16 + e] += ph[8]*s0 + ph[9]*s1 + ph[10]*s2;
        }
      }
    }
    // 220: d input (k-split for registers)
    for (int kh = 0; kh < 2; ++kh) {
      float z[4][9][2];
      zcompute2_k4<128,64>(Pt + OFF_220, xd0, xd1, o, kh, z);
      for (int a = 0; a < 2; ++a) {
        const int E = a ? E1 : E0;
        for (int e = 0; e < E; ++e) {
          const float* ph = &sphi[(a*16 + e)*12];
          const float* rr = ph + kh*4;
          float s[9];
#pragma unroll
          for (int m = 0; m < 9; ++m) s[m] = kdot2_k4(z, m, a, rr);
          const float q0 = ph[8], q1 = ph[9], q2 = ph[10];
          psi[a*16 + e] += q0*(q0*s[0] + q1*s[1] + q2*s[2])
                         + q1*(q0*s[3] + q1*s[4] + q2*s[5])
                         + q2*(q0*s[6] + q1*s[7] + q2*s[8]);
        }
      }
    }
    for (int e = 0; e < E0; ++e)
      psiA[(size_t)(off0 + b0 + e)*256 + l*128 + o] = psi[e];
    for (int e = 0; e < E1; ++e)
      psiA[(size_t)(off1 + b0 + e)*256 + l*128 + o] = psi[16 + e];
  }
}

// ---------------------------------------------------------------------------
// Pass V: psi_v (011,101,121,211,111). One block per atom pair. 192 thr.
// ---------------------------------------------------------------------------
__global__ __launch_bounds__(192, 2) void pass_v_kernel(
    const int* __restrict__ off, const float* __restrict__ phi,
    const float* __restrict__ Pt,
    const float* __restrict__ a_ws, const float* __restrict__ v_ws, const float* __restrict__ d_ws,
    float* __restrict__ psiV)
{
  __shared__ float sm[3968 + 384];
  const int t = threadIdx.x;
  const int n0 = blockIdx.x * 2, n1 = n0 + 1;
  const int off0 = off[n0], off1 = off[n1], off2 = off[n1 + 1];
  const int d0 = off1 - off0, d1 = off2 - off1;
  const int dm = d0 > d1 ? d0 : d1;
  if (dm == 0) return;
  const int o = t % 96, l = t / 96;
  load_features<192>(sm, t, n0, n1, a_ws, v_ws, d_ws);
  const float* xa0 = &sm[F_XA + l*128];
  const float* xa1 = &sm[F_XA + 256 + l*128];
  const float* xv0 = &sm[F_XV + l*288];
  const float* xv1 = &sm[F_XV + 576 + l*288];
  const float* xd0 = &sm[F_XD + l*576];
  const float* xd1 = &sm[F_XD + 1152 + l*576];
  float* sphi = &sm[F_PHI];

  const int nw = (dm + 15) >> 4;
  for (int w = 0; w < nw; ++w) {
    const int b0 = w * 16;
    const int E0 = min(16, max(0, d0 - b0));
    const int E1 = min(16, max(0, d1 - b0));
    __syncthreads();
    for (int q = t; q < 384; q += 192) {
      const int s = q / 12, f = q % 12, a = s >> 4, e = s & 15;
      const int E = a ? E1 : E0;
      const int gp = (a ? off1 : off0) + b0 + e;
      sphi[q] = (e < E) ? phi[(size_t)gp * 12 + f] : 0.f;
    }
    __syncthreads();
    float psi[32][3];
#pragma unroll
    for (int i = 0; i < 32; ++i) { psi[i][0] = 0.f; psi[i][1] = 0.f; psi[i][2] = 0.f; }

    { // 011: v direct
      float z[8][3][2];
      zcompute2<96,96,3>(Pt + OFF_011, xv0, xv1, o, z);
      for (int a = 0; a < 2; ++a) {
        const int E = a ? E1 : E0;
        for (int e = 0; e < E; ++e) {
          const float* ph = &sphi[(a*16 + e)*12];
          psi[a*16+e][0] += kdot2<3>(z, 0, a, ph);
          psi[a*16+e][1] += kdot2<3>(z, 1, a, ph);
          psi[a*16+e][2] += kdot2<3>(z, 2, a, ph);
        }
      }
    }
    { // 101: a, * rh_i
      float z[8][1][2];
      zcompute2<96,128,1>(Pt + OFF_101, xa0, xa1, o, z);
      for (int a = 0; a < 2; ++a) {
        const int E = a ? E1 : E0;
        for (int e = 0; e < E; ++e) {
          const float* ph = &sphi[(a*16 + e)*12];
          const float s0 = kdot2<1>(z, 0, a, ph);
          psi[a*16+e][0] += ph[8]*s0; psi[a*16+e][1] += ph[9]*s0; psi[a*16+e][2] += ph[10]*s0;
        }
      }
    }
    // 121: d, psi_i += sum_j rh_j s[3i+j]  (k-split)
    for (int kh = 0; kh < 2; ++kh) {
      float z[4][9][2];
      zcompute2_k4<96,64>(Pt + OFF_121, xd0, xd1, o, kh, z);
      for (int a = 0; a < 2; ++a) {
        const int E = a ? E1 : E0;
        for (int e = 0; e < E; ++e) {
          const float* ph = &sphi[(a*16 + e)*12];
          const float* rr = ph + kh*4;
          float s[9];
#pragma unroll
          for (int m = 0; m < 9; ++m) s[m] = kdot2_k4(z, m, a, rr);
          const float q0 = ph[8], q1 = ph[9], q2 = ph[10];
          psi[a*16+e][0] += q0*s[0] + q1*s[1] + q2*s[2];
          psi[a*16+e][1] += q0*s[3] + q1*s[4] + q2*s[5];
          psi[a*16+e][2] += q0*s[6] + q1*s[7] + q2*s[8];
        }
      }
    }
    { // 211: v, rh_i * (rh . s)
      float z[8][3][2];
      zcompute2<96,96,3>(Pt + OFF_211, xv0, xv1, o, z);
      for (int a = 0; a < 2; ++a) {
        const int E = a ? E1 : E0;
        for (int e = 0; e < E; ++e) {
          const float* ph = &sphi[(a*16 + e)*12];
          const float tt = ph[8]*kdot2<3>(z,0,a,ph) + ph[9]*kdot2<3>(z,1,a,ph) + ph[10]*kdot2<3>(z,2,a,ph);
          psi[a*16+e][0] += ph[8]*tt; psi[a*16+e][1] += ph[9]*tt; psi[a*16+e][2] += ph[10]*tt;
        }
      }
    }
    { // 111: v, rh x s
      float z[8][3][2];
      zcompute2<96,96,3>(Pt + OFF_111, xv0, xv1, o, z);
      for (int a = 0; a < 2; ++a) {
        const int E = a ? E1 : E0;
        for (int e = 0; e < E; ++e) {
          const float* ph = &sphi[(a*16 + e)*12];
          const float s0 = kdot2<3>(z,0,a,ph), s1 = kdot2<3>(z,1,a,ph), s2 = kdot2<3>(z,2,a,ph);
          const float q0 = ph[8], q1 = ph[9], q2 = ph[10];
          psi[a*16+e][0] += q1*s2 - q2*s1;
          psi[a*16+e][1] += q2*s0 - q0*s2;
          psi[a*16+e][2] += q0*s1 - q1*s0;
        }
      }
    }
    for (int e = 0; e < E0; ++e) {
      float* d = &psiV[(size_t)(off0 + b0 + e)*576 + l*288 + o*3];
      d[0] = psi[e][0]; d[1] = psi[e][1]; d[2] = psi[e][2];
    }
    for (int e = 0; e < E1; ++e) {
      float* d = &psiV[(size_t)(off1 + b0 + e)*576 + l*288 + o*3];
      d[0] = psi[16+e][0]; d[1] = psi[16+e][1]; d[2] = psi[16+e][2];
    }
  }
}

// ---------------------------------------------------------------------------
// Pass D: psi_d (022,202,112,222,212). One block per atom pair. 256 thr:
// t = o(64) | l(2) | atom(2); each thread owns one atom, window of 8 edges.
// ---------------------------------------------------------------------------
__global__ __launch_bounds__(256, 2) void pass_d_kernel(
    const int* __restrict__ off, const float* __restrict__ phi, const int* __restrict__ srcs,
    const float* __restrict__ Pt,
    const float* __restrict__ a_ws, const float* __restrict__ v_ws, const float* __restrict__ d_ws,
    float* __restrict__ Bd)
{
  __shared__ float sm[3968 + 192];
  __shared__ int s_src[16];
  const int t = threadIdx.x;
  const int n0 = blockIdx.x * 2, n1 = n0 + 1;
  const int off0 = off[n0], off1 = off[n1], off2 = off[n1 + 1];
  const int d0 = off1 - off0, d1 = off2 - off1;
  const int dm = d0 > d1 ? d0 : d1;
  if (dm == 0) return;
  const int o = t & 63, l = (t >> 6) & 1, a = t >> 7;
  load_features<256>(sm, t, n0, n1, a_ws, v_ws, d_ws);
  const float* xa = &sm[F_XA + a*256 + l*128];
  const float* xv = &sm[F_XV + a*576 + l*288];
  const float* xd = &sm[F_XD + a*1152 + l*576];
  float* sphi = &sm[F_PHI];
  const int offa = a ? off1 : off0;

  const int nw = (dm + 7) >> 3;
  for (int w = 0; w < nw; ++w) {
    const int b0 = w * 8;
    const int E0 = min(8, max(0, d0 - b0));
    const int E1 = min(8, max(0, d1 - b0));
    const int Ea = a ? E1 : E0;
    __syncthreads();
    for (int q = t; q < 192; q += 256) {
      const int s = q / 12, f = q % 12, a2 = s >> 3, e = s & 7;
      const int E = a2 ? E1 : E0;
      const int gp = (a2 ? off1 : off0) + b0 + e;
      sphi[q] = (e < E) ? phi[(size_t)gp * 12 + f] : 0.f;
    }
    if (t < 16) {
      const int a2 = t >> 3, e = t & 7;
      const int E = a2 ? E1 : E0;
      s_src[t] = (e < E) ? srcs[(a2 ? off1 : off0) + b0 + e] : 0;
    }
    __syncthreads();
    float psi[8][9];
#pragma unroll
    for (int i = 0; i < 8; ++i)
#pragma unroll
      for (int j = 0; j < 9; ++j) psi[i][j] = 0.f;

    { // 022: d direct
      float z[8][9];
      zcompute<64,64,9>(Pt + OFF_022, xd, o, z);
      for (int e = 0; e < Ea; ++e) {
        const float* ph = &sphi[(a*8 + e)*12];
#pragma unroll
        for (int m = 0; m < 9; ++m) psi[e][m] += kdot<9>(z, m, ph);
      }
    }
    { // 202: a, q_i q_j s
      float z[8][1];
      zcompute<64,128,1>(Pt + OFF_202, xa, o, z);
      for (int e = 0; e < Ea; ++e) {
        const float* ph = &sphi[(a*8 + e)*12];
        const float s0 = kdot<1>(z, 0, ph);
        const float q0 = ph[8], q1 = ph[9], q2 = ph[10];
        psi[e][0] += q0*q0*s0; psi[e][1] += q0*q1*s0; psi[e][2] += q0*q2*s0;
        psi[e][3] += q1*q0*s0; psi[e][4] += q1*q1*s0; psi[e][5] += q1*q2*s0;
        psi[e][6] += q2*q0*s0; psi[e][7] += q2*q1*s0; psi[e][8] += q2*q2*s0;
      }
    }
    { // 112: v, q_i s_j
      float z[8][3];
      zcompute<64,96,3>(Pt + OFF_112, xv, o, z);
      for (int e = 0; e < Ea; ++e) {
        const float* ph = &sphi[(a*8 + e)*12];
        const float s0 = kdot<3>(z,0,ph), s1 = kdot<3>(z,1,ph), s2 = kdot<3>(z,2,ph);
        const float q0 = ph[8], q1 = ph[9], q2 = ph[10];
        psi[e][0] += q0*s0; psi[e][1] += q0*s1; psi[e][2] += q0*s2;
        psi[e][3] += q1*s0; psi[e][4] += q1*s1; psi[e][5] += q1*s2;
        psi[e][6] += q2*s0; psi[e][7] += q2*s1; psi[e][8] += q2*s2;
      }
    }
    { // 222: d, u_j = sum_k q_k s[3k+j]; psi[ij] += q_i u_j
      float z[8][9];
      zcompute<64,64,9>(Pt + OFF_222, xd, o, z);
      for (int e = 0; e < Ea; ++e) {
        const float* ph = &sphi[(a*8 + e)*12];
        float s[9];
#pragma unroll
        for (int m = 0; m < 9; ++m) s[m] = kdot<9>(z, m, ph);
        const float q0 = ph[8], q1 = ph[9], q2 = ph[10];
        const float u0 = q0*s[0] + q1*s[3] + q2*s[6];
        const float u1 = q0*s[1] + q1*s[4] + q2*s[7];
        const float u2 = q0*s[2] + q1*s[5] + q2*s[8];
        psi[e][0] += q0*u0; psi[e][1] += q0*u1; psi[e][2] += q0*u2;
        psi[e][3] += q1*u0; psi[e][4] += q1*u1; psi[e][5] += q1*u2;
        psi[e][6] += q2*u0; psi[e][7] += q2*u1; psi[e][8] += q2*u2;
      }
    }
    { // 212: v, c = q x s; psi[ij] += c_i q_j
      float z[8][3];
      zcompute<64,96,3>(Pt + OFF_212, xv, o, z);
      for (int e = 0; e < Ea; ++e) {
        const float* ph = &sphi[(a*8 + e)*12];
        const float s0 = kdot<3>(z,0,ph), s1 = kdot<3>(z,1,ph), s2 = kdot<3>(z,2,ph);
        const float q0 = ph[8], q1 = ph[9], q2 = ph[10];
        const float c0 = q1*s2 - q2*s1;
        const float c1 = q2*s0 - q0*s2;
        const float c2 = q0*s1 - q1*s0;
        psi[e][0] += c0*q0; psi[e][1] += c0*q1; psi[e][2] += c0*q2;
        psi[e][3] += c1*q0; psi[e][4] += c1*q1; psi[e][5] += c1*q2;
        psi[e][6] += c2*q0; psi[e][7] += c2*q1; psi[e][8] += c2*q2;
      }
    }
    for (int e = 0; e < Ea; ++e) {
      float* bp = &Bd[((size_t)l*NA + s_src[a*8 + e])*576 + o*9];
#pragma unroll
      for (int j = 0; j < 9; ++j) unsafeAtomicAdd(bp + j, psi[e][j]);
    }
  }
}

// ---------------------------------------------------------------------------
// Scalar MLP + scatter (48 combos/block; combo = sorted_slot*2 + l)
// ---------------------------------------------------------------------------
__global__ __launch_bounds__(256, 2) void mlp_a_kernel(
    const float* __restrict__ psiA, const int* __restrict__ srcs,
    const float* __restrict__ Wd_a,
    const float* __restrict__ W1, const float* __restrict__ b1,
    const float* __restrict__ W2, const float* __restrict__ b2,
    const float* __restrict__ W3, const float* __restrict__ b3,
    float* __restrict__ Ba)
{
  __shared__ float PA[48*128];
  __shared__ float H1[48*256];
  __shared__ float H2[48*256];
  const int t = threadIdx.x;
  const int cbase = blockIdx.x * 48;
  const int ncl = min(48, 2*NE - cbase);

  for (int q = t; q < 48*128; q += 256) {
    int j = q >> 7;
    PA[q] = (j < ncl) ? psiA[(size_t)(cbase + j)*128 + (q & 127)] : 0.f;
  }
  __syncthreads();
  {
    const float* Wr = &W1[(size_t)t * 128];
    const float bb = b1[t];
    for (int c0 = 0; c0 < 48; c0 += 8) {
      float acc[8] = {0,0,0,0,0,0,0,0};
      for (int c = 0; c < 128; c += 4) {
        const float4 w4 = *(const float4*)&Wr[c];
#pragma unroll
        for (int j = 0; j < 8; ++j)
          acc[j] += dot4f(w4, *(const float4*)&PA[(c0 + j)*128 + c]);
      }
#pragma unroll
      for (int j = 0; j < 8; ++j) H1[(c0 + j)*256 + t] = lrelu(acc[j] + bb);
    }
  }
  __syncthreads();
  {
    const float* Wr = &W2[(size_t)t * 256];
    const float bb = b2[t];
    for (int c0 = 0; c0 < 48; c0 += 8) {
      float acc[8] = {0,0,0,0,0,0,0,0};
      for (int c = 0; c < 256; c += 4) {
        const float4 w4 = *(const float4*)&Wr[c];
#pragma unroll
        for (int j = 0; j < 8; ++j)
          acc[j] += dot4f(w4, *(const float4*)&H1[(c0 + j)*256 + c]);
      }
#pragma unroll
      for (int j = 0; j < 8; ++j) H2[(c0 + j)*256 + t] = lrelu(acc[j] + bb);
    }
  }
  __syncthreads();
  {
    const int o = t & 127, g = t >> 7;
    const float* Wdr = &Wd_a[(size_t)o * 128];
    const float* W3r = &W3[(size_t)o * 256];
    const float bb = b3[o];
    for (int c0 = g*24; c0 < g*24 + 24; c0 += 8) {
      float acc[8] = {0,0,0,0,0,0,0,0};
      for (int c = 0; c < 128; c += 4) {
        const float4 w4 = *(const float4*)&Wdr[c];
#pragma unroll
        for (int j = 0; j < 8; ++j)
          acc[j] += dot4f(w4, *(const float4*)&PA[(c0 + j)*128 + c]);
      }
      for (int c = 0; c < 256; c += 4) {
        const float4 w4 = *(const float4*)&W3r[c];
#pragma unroll
        for (int j = 0; j < 8; ++j)
          acc[j] += dot4f(w4, *(const float4*)&H2[(c0 + j)*256 + c]);
      }
#pragma unroll
      for (int j = 0; j < 8; ++j) {
        if (c0 + j < ncl) {
          const int cid = cbase + c0 + j;
          const int p = cid >> 1, l = cid & 1;
          const float val = acc[j] + bb + PA[(c0 + j)*128 + o];
          unsafeAtomicAdd(&Ba[((size_t)l*NA + srcs[p])*128 + o], val);
        }
      }
    }
  }
}

// ---------------------------------------------------------------------------
// Vector MLP + scatter (24 combos/block)
// ---------------------------------------------------------------------------
__global__ __launch_bounds__(256, 2) void mlp_v_kernel(
    const float* __restrict__ psiV, const int* __restrict__ srcs,
    const float* __restrict__ Vd, const float* __restrict__ V1,
    const float* __restrict__ V2, const float* __restrict__ V3,
    float* __restrict__ Bv)
{
  __shared__ float PV[24*288];
  __shared__ float HV[24*576];
  __shared__ float HV2[24*576];
  const int t = threadIdx.x;
  const int cbase = blockIdx.x * 24;
  const int ncl = min(24, 2*NE - cbase);

  for (int q = t; q < 24*288; q += 256) {
    const int j = q / 288, r = q % 288;
    const float val = (j < ncl) ? psiV[(size_t)(cbase + j)*288 + r] : 0.f;
    PV[j*288 + (r % 3)*96 + r/3] = val;
  }
  __syncthreads();
  if (t < 192) {
    const float* Vr = &V1[(size_t)t * 96];
    for (int c0 = 0; c0 < 24; c0 += 4) {
      float acc[4][3] = {};
      for (int c = 0; c < 96; c += 4) {
        const float4 w4 = *(const float4*)&Vr[c];
#pragma unroll
        for (int j = 0; j < 4; ++j)
#pragma unroll
          for (int i = 0; i < 3; ++i)
            acc[j][i] += dot4f(w4, *(const float4*)&PV[(c0 + j)*288 + i*96 + c]);
      }
#pragma unroll
      for (int j = 0; j < 4; ++j) {
        const float nn = sqrtf(acc[j][0]*acc[j][0] + acc[j][1]*acc[j][1] + acc[j][2]*acc[j][2] + 1e-12f);
        const float sc = (2.f / (1.f + expf(-nn)) - 1.f) / nn;
#pragma unroll
        for (int i = 0; i < 3; ++i) HV[(c0 + j)*576 + i*192 + t] = acc[j][i]*sc;
      }
    }
  }
  __syncthreads();
  if (t < 192) {
    const float* Vr = &V2[(size_t)t * 192];
    for (int c0 = 0; c0 < 24; c0 += 4) {
      float acc[4][3] = {};
      for (int c = 0; c < 192; c += 4) {
        const float4 w4 = *(const float4*)&Vr[c];
#pragma unroll
        for (int j = 0; j < 4; ++j)
#pragma unroll
          for (int i = 0; i < 3; ++i)
            acc[j][i] += dot4f(w4, *(const float4*)&HV[(c0 + j)*576 + i*192 + c]);
      }
#pragma unroll
      for (int j = 0; j < 4; ++j) {
        const float nn = sqrtf(acc[j][0]*acc[j][0] + acc[j][1]*acc[j][1] + acc[j][2]*acc[j][2] + 1e-12f);
        const float sc = (2.f / (1.f + expf(-nn)) - 1.f) / nn;
#pragma unroll
        for (int i = 0; i < 3; ++i) HV2[(c0 + j)*576 + i*192 + t] = acc[j][i]*sc;
      }
    }
  }
  __syncthreads();
  if (t < 192) {
    const int o = t % 96, g = t / 96;
    const float* Vdr = &Vd[(size_t)o * 96];
    const float* V3r = &V3[(size_t)o * 192];
    for (int c0 = g*12; c0 < g*12 + 12; c0 += 4) {
      float acc[4][3] = {};
      for (int c = 0; c < 96; c += 4) {
        const float4 w4 = *(const float4*)&Vdr[c];
#pragma unroll
        for (int j = 0; j < 4; ++j)
#pragma unroll
          for (int i = 0; i < 3; ++i)
            acc[j][i] += dot4f(w4, *(const float4*)&PV[(c0 + j)*288 + i*96 + c]);
      }
      for (int c = 0; c < 192; c += 4) {
        const float4 w4 = *(const float4*)&V3r[c];
#pragma unroll
        for (int j = 0; j < 4; ++j)
#pragma unroll
          for (int i = 0; i < 3; ++i)
            acc[j][i] += dot4f(w4, *(const float4*)&HV2[(c0 + j)*576 + i*192 + c]);
      }
#pragma unroll
      for (int j = 0; j < 4; ++j) {
        if (c0 + j < ncl) {
          const int cid = cbase + c0 + j;
          const int p = cid >> 1, l = cid & 1;
          const int s = srcs[p];
#pragma unroll
          for (int i = 0; i < 3; ++i) {
            const float val = acc[j][i] + PV[(c0 + j)*288 + i*96 + o];
            unsafeAtomicAdd(&Bv[((size_t)l*NA + s)*288 + o*3 + i], val);
          }
        }
      }
    }
  }
}

// ---------------------------------------------------------------------------
// Output projection (per atom)
// ---------------------------------------------------------------------------
__global__ __launch_bounds__(256) void proj_out_kernel(
    const float* __restrict__ Ba, const float* __restrict__ Bv, const float* __restrict__ Bd,
    const float* __restrict__ Wa, const float* __restrict__ Wv, const float* __restrict__ Wd,
    float* __restrict__ out)
{
  __shared__ float bs[256 + 576 + 1152];
  const int n = blockIdx.x, t = threadIdx.x;
  for (int q = t; q < 256; q += 256)
    bs[q] = Ba[((size_t)(q >> 7)*NA + n)*128 + (q & 127)];
  for (int q = t; q < 576; q += 256)
    bs[256 + q] = Bv[((size_t)(q / 288)*NA + n)*288 + (q % 288)];
  for (int q = t; q < 1152; q += 256)
    bs[832 + q] = Bd[((size_t)(q / 576)*NA + n)*576 + (q % 576)];
  __syncthreads();
  if (t < 128) {
    const float* W = &Wa[(size_t)t * 256];
    float acc = 0.f;
    for (int c = 0; c < 256; c += 4) acc += dot4f(*(const float4*)&W[c], *(const float4*)&bs[c]);
    out[(size_t)n*128 + t] = acc;
  }
  if (t < 96) {
    const float* W = &Wv[(size_t)t * 192];
    float a0 = 0.f, a1 = 0.f, a2 = 0.f;
    for (int c = 0; c < 192; ++c) {
      const float w = W[c]; const float* x = &bs[256 + c*3];
      a0 = fmaf(w, x[0], a0); a1 = fmaf(w, x[1], a1); a2 = fmaf(w, x[2], a2);
    }
    float* d = &out[OUT_V + ((size_t)n*96 + t)*3];
    d[0] = a0; d[1] = a1; d[2] = a2;
  }
  if (t < 64) {
    const float* W = &Wd[(size_t)t * 128];
    float acc[9] = {0,0,0,0,0,0,0,0,0};
    for (int c = 0; c < 128; ++c) {
      const float w = W[c]; const float* x = &bs[832 + c*9];
#pragma unroll
      for (int j = 0; j < 9; ++j) acc[j] = fmaf(w, x[j], acc[j]);
    }
    float* d = &out[OUT_D + ((size_t)n*64 + t)*9];
#pragma unroll
    for (int j = 0; j < 9; ++j) d[j] = acc[j];
  }
}

// ---------------------------------------------------------------------------
// Host entry
// ---------------------------------------------------------------------------
extern "C" void kernel_launch(void* const* d_in, const int* in_sizes, int n_in,
                              void* d_out, int out_size, void* d_ws, size_t ws_size,
                              hipStream_t stream) {
  (void)in_sizes; (void)n_in; (void)out_size; (void)ws_size;
  const int*   src  = (const int*)d_in[0];
  const int*   dst  = (const int*)d_in[1];
  const float* r_ij = (const float*)d_in[2];
  const float* x_a  = (const float*)d_in[3];
  const float* x_v  = (const float*)d_in[4];
  const float* x_d  = (const float*)d_in[5];
  const float* P[13];
  for (int i = 0; i < 13; ++i) P[i] = (const float*)d_in[6 + i];
  const float* W_in_a  = (const float*)d_in[19];
  const float* W_in_v  = (const float*)d_in[20];
  const float* W_in_d  = (const float*)d_in[21];
  const float* W_out_a = (const float*)d_in[22];
  const float* W_out_v = (const float*)d_in[23];
  const float* W_out_d = (const float*)d_in[24];
  const float* Wd_a = (const float*)d_in[25];
  const float* W1   = (const float*)d_in[26];
  const float* b1   = (const float*)d_in[27];
  const float* W2   = (const float*)d_in[28];
  const float* b2   = (const float*)d_in[29];
  const float* W3   = (const float*)d_in[30];
  const float* b3   = (const float*)d_in[31];
  const float* Vd   = (const float*)d_in[32];
  const float* V1   = (const float*)d_in[33];
  const float* V2   = (const float*)d_in[34];
  const float* V3   = (const float*)d_in[35];

  float* ws = (float*)d_ws;
  float* Pt = ws;
  int*   ib = (int*)(ws + INT_OFF);

  // 1) transpose P tensors to [C][O][8]
  static const int Od[13] = {128,128,128, 96, 96, 96, 96, 96, 64, 64, 64, 64, 64};
  static const int Cd[13] = {128, 96, 64, 96,128, 64, 96, 96, 64,128, 96, 64, 96};
  for (int i = 0; i < 13; ++i) {
    const int total = Od[i] * Cd[i];
    transposeP_kernel<<<(total + 255) / 256, 256, 0, stream>>>(P[i], Pt + POFF[i], Od[i], Cd[i]);
  }

  // 2) zero scatter accumulators + sort counters
  hipMemsetAsync(ws + BA_OFF, 0, (size_t)(PHI_OFF - BA_OFF) * sizeof(float), stream);
  hipMemsetAsync(ib, 0, (size_t)(ICUR + NA) * sizeof(int), stream);

  // 3) counting sort by dst + per-edge radial/vector encodings
  const int egrid = (NE + 255) / 256;
  hist_kernel<<<egrid, 256, 0, stream>>>(dst, ib + ICNT);
  scan_kernel<<<1, 256, 0, stream>>>(ib + ICNT, ib + IOFF);
  sort_scatter_kernel<<<egrid, 256, 0, stream>>>(dst, ib + IOFF, ib + ICUR, ib + IEIDX);
  phi_kernel<<<egrid, 256, 0, stream>>>(ib + IEIDX, src, r_ij, ws + PHI_OFF, ib + ISRC);

  // 4) input projections
  proj_in_kernel<<<NA, 256, 0, stream>>>(x_a, x_v, x_d, W_in_a, W_in_v, W_in_d,
                                         ws + A_OFF, ws + V_OFF, ws + D_OFF);

  // 5) messages: three rank-specialized passes, one block per atom pair
  pass_a_kernel<<<NA/2, 256, 0, stream>>>(ib + IOFF, ws + PHI_OFF, Pt,
                                          ws + A_OFF, ws + V_OFF, ws + D_OFF,
                                          ws + PSIA_OFF);
  pass_v_kernel<<<NA/2, 192, 0, stream>>>(ib + IOFF, ws + PHI_OFF, Pt,
                                          ws + A_OFF, ws + V_OFF, ws + D_OFF,
                                          ws + PSIV_OFF);
  pass_d_kernel<<<NA/2, 256, 0, stream>>>(ib + IOFF, ws + PHI_OFF, ib + ISRC, Pt,
                                          ws + A_OFF, ws + V_OFF, ws + D_OFF,
                                          ws + BD_OFF);

  // 6) edge MLPs + scatter
  mlp_a_kernel<<<(2*NE + 47) / 48, 256, 0, stream>>>(ws + PSIA_OFF, ib + ISRC,
                                                     Wd_a, W1, b1, W2, b2, W3, b3,
                                                     ws + BA_OFF);
  mlp_v_kernel<<<(2*NE + 23) / 24, 256, 0, stream>>>(ws + PSIV_OFF, ib + ISRC,
                                                     Vd, V1, V2, V3,
                                                     ws + BV_OFF);

  // 7) output projections
  proj_out_kernel<<<NA, 256, 0, stream>>>(ws + BA_OFF, ws + BV_OFF, ws + BD_OFF,
                                          W_out_a, W_out_v, W_out_d, (float*)d_out);
}